// Round 11
// baseline (531.995 us; speedup 1.0000x reference)
//
#include <hip/hip_runtime.h>
#include <cstdint>
#include <cstddef>

#define F_IN   128
#define SLOPE  0.2f

typedef unsigned short u16;
typedef __attribute__((ext_vector_type(8))) short     bf16x8;
typedef __attribute__((ext_vector_type(8))) unsigned short u16x8;
typedef __attribute__((ext_vector_type(4))) unsigned short u16x4;
typedef __attribute__((ext_vector_type(4))) float     f32x4;

// ---------- float -> bf16 (round-to-nearest-even) ----------
__device__ __forceinline__ u16 f2bf(float f) {
    unsigned u = __float_as_uint(f);
    unsigned r = u + 0x7FFFu + ((u >> 16) & 1u);
    return (u16)(r >> 16);
}
__device__ __forceinline__ float bf2f(u16 h) {
    return __uint_as_float(((unsigned)h) << 16);
}

__device__ __forceinline__ float lrelu(float v) { return v >= 0.f ? v : SLOPE * v; }

// ---------------- alpha dot products (bf16 h) ----------------
__global__ void alphas0_k(const u16* __restrict__ h0, const float* __restrict__ a_src,
                          const float* __restrict__ a_dst, float* __restrict__ asrc,
                          float* __restrict__ adst, int N) {
    int gid = blockIdx.x * blockDim.x + threadIdx.x;
    int n = gid >> 6, lane = gid & 63;
    if (n >= N) return;
    #pragma unroll
    for (int h = 0; h < 4; ++h) {
        float v  = bf2f(h0[(size_t)n * 256 + h * 64 + lane]);
        float s1 = v * a_src[h * 64 + lane];
        float s2 = v * a_dst[h * 64 + lane];
        #pragma unroll
        for (int off = 32; off; off >>= 1) {
            s1 += __shfl_down(s1, off);
            s2 += __shfl_down(s2, off);
        }
        if (lane == 0) { asrc[n * 4 + h] = s1; adst[n * 4 + h] = s2; }
    }
}

__global__ void alphas1_k(const u16* __restrict__ h1, const float* __restrict__ a_src,
                          const float* __restrict__ a_dst, float* __restrict__ asrc,
                          float* __restrict__ adst, int N) {
    int gid = blockIdx.x * blockDim.x + threadIdx.x;
    int n = gid >> 6, lane = gid & 63;
    if (n >= N) return;
    float s1 = 0.f, s2 = 0.f;
    #pragma unroll
    for (int k = 0; k < 4; ++k) {
        float v = bf2f(h1[(size_t)n * 256 + k * 64 + lane]);
        s1 += v * a_src[k * 64 + lane];
        s2 += v * a_dst[k * 64 + lane];
    }
    #pragma unroll
    for (int off = 32; off; off >>= 1) {
        s1 += __shfl_down(s1, off);
        s2 += __shfl_down(s2, off);
    }
    if (lane == 0) { asrc[n] = s1; adst[n] = s2; }
}

// ---------------- CSR build (by destination; valid edges + self-loops) ----------------
__global__ void deg_init(int* __restrict__ deg, int N) {
    int i = blockIdx.x * blockDim.x + threadIdx.x;
    if (i < N) deg[i] = 1;                      // self-loop
}

__global__ void count_deg(const int* __restrict__ ei, int* __restrict__ deg, int E) {
    int e = blockIdx.x * blockDim.x + threadIdx.x;
    if (e >= E) return;
    int s = ei[e], d = ei[E + e];
    if (s != d) atomicAdd(&deg[d], 1);
}

__global__ void scan1(const int* __restrict__ deg, int* __restrict__ part,
                      int* __restrict__ bsum, int N) {
    __shared__ int sm[256];
    int i = blockIdx.x * 256 + threadIdx.x;
    int v = (i < N) ? deg[i] : 0;
    sm[threadIdx.x] = v; __syncthreads();
    for (int off = 1; off < 256; off <<= 1) {
        int tv = (threadIdx.x >= off) ? sm[threadIdx.x - off] : 0;
        __syncthreads();
        sm[threadIdx.x] += tv;
        __syncthreads();
    }
    if (i < N) part[i] = sm[threadIdx.x] - v;   // exclusive within block
    if (threadIdx.x == 255) bsum[blockIdx.x] = sm[255];
}

__global__ void scan2(int* __restrict__ bsum, int nb) {
    __shared__ int sm[256];
    __shared__ int carry;
    if (threadIdx.x == 0) carry = 0;
    __syncthreads();
    for (int base = 0; base < nb; base += 256) {
        int i = base + threadIdx.x;
        int v = (i < nb) ? bsum[i] : 0;
        sm[threadIdx.x] = v; __syncthreads();
        for (int off = 1; off < 256; off <<= 1) {
            int tv = (threadIdx.x >= off) ? sm[threadIdx.x - off] : 0;
            __syncthreads();
            sm[threadIdx.x] += tv;
            __syncthreads();
        }
        if (i < nb) bsum[i] = sm[threadIdx.x] - v + carry;
        __syncthreads();
        if (threadIdx.x == 0) carry += sm[255];
        __syncthreads();
    }
}

__global__ void scan3(const int* __restrict__ deg, const int* __restrict__ part,
                      const int* __restrict__ bsum, int* __restrict__ rowp,
                      int* __restrict__ cursor, int N) {
    int i = blockIdx.x * blockDim.x + threadIdx.x;
    if (i >= N) return;
    int r = part[i] + bsum[i >> 8];
    rowp[i] = r;
    cursor[i] = r;
    if (i == N - 1) rowp[N] = r + deg[i];
}

__global__ void scatter_k(const int* __restrict__ ei, int* __restrict__ cursor,
                          int* __restrict__ csr, int E, int N) {
    int e = blockIdx.x * blockDim.x + threadIdx.x;
    if (e >= E + N) return;
    int s, d;
    if (e < E) { s = ei[e]; d = ei[E + e]; if (s == d) return; }
    else       { s = d = e - E; }
    int pos = atomicAdd(&cursor[d], 1);
    csr[pos] = s;
}

// ---------------- GAT gather-aggregate (bf16 features; fused softmax/agg/norm/bias/relu) ----
__global__ void gat_gather0(const int* __restrict__ csr, const int* __restrict__ rowp,
                            const u16* __restrict__ h0, const float* __restrict__ asrc,
                            const float* __restrict__ adst, const float* __restrict__ b,
                            float* __restrict__ outx, int N) {
    int gid = blockIdx.x * blockDim.x + threadIdx.x;
    int n = gid >> 6, lane = gid & 63;
    if (n >= N) return;
    int beg = rowp[n], end = rowp[n + 1];
    float4 ad = *(const float4*)(adst + (size_t)n * 4);
    float m0 = -1e30f, m1 = -1e30f, m2 = -1e30f, m3 = -1e30f;
    for (int i = beg + lane; i < end; i += 64) {
        int s = csr[i];
        float4 as = *(const float4*)(asrc + (size_t)s * 4);
        m0 = fmaxf(m0, lrelu(as.x + ad.x));
        m1 = fmaxf(m1, lrelu(as.y + ad.y));
        m2 = fmaxf(m2, lrelu(as.z + ad.z));
        m3 = fmaxf(m3, lrelu(as.w + ad.w));
    }
    #pragma unroll
    for (int off = 32; off; off >>= 1) {
        m0 = fmaxf(m0, __shfl_xor(m0, off));
        m1 = fmaxf(m1, __shfl_xor(m1, off));
        m2 = fmaxf(m2, __shfl_xor(m2, off));
        m3 = fmaxf(m3, __shfl_xor(m3, off));
    }
    float acc0 = 0.f, acc1 = 0.f, acc2 = 0.f, acc3 = 0.f;
    float den0 = 0.f, den1 = 0.f, den2 = 0.f, den3 = 0.f;
    for (int i = beg; i < end; ++i) {
        int s = csr[i];
        float4 as = *(const float4*)(asrc + (size_t)s * 4);
        float w0 = __expf(lrelu(as.x + ad.x) - m0);
        float w1 = __expf(lrelu(as.y + ad.y) - m1);
        float w2 = __expf(lrelu(as.z + ad.z) - m2);
        float w3 = __expf(lrelu(as.w + ad.w) - m3);
        den0 += w0; den1 += w1; den2 += w2; den3 += w3;
        const u16* hs = h0 + (size_t)s * 256;
        acc0 += w0 * bf2f(hs[lane]);
        acc1 += w1 * bf2f(hs[64 + lane]);
        acc2 += w2 * bf2f(hs[128 + lane]);
        acc3 += w3 * bf2f(hs[192 + lane]);
    }
    float* po = outx + (size_t)n * 256;
    float v;
    v = acc0 / den0 + b[lane];       po[lane]       = v > 0.f ? v : 0.f;
    v = acc1 / den1 + b[64 + lane];  po[64 + lane]  = v > 0.f ? v : 0.f;
    v = acc2 / den2 + b[128 + lane]; po[128 + lane] = v > 0.f ? v : 0.f;
    v = acc3 / den3 + b[192 + lane]; po[192 + lane] = v > 0.f ? v : 0.f;
}

// layer1: writes m0 directly as bf16 (mlp_mfma rounds to bf16 anyway -> exact-equivalent)
__global__ void gat_gather1(const int* __restrict__ csr, const int* __restrict__ rowp,
                            const u16* __restrict__ h1, const float* __restrict__ asrc,
                            const float* __restrict__ adst, const float* __restrict__ b,
                            u16* __restrict__ outx, int N) {
    int gid = blockIdx.x * blockDim.x + threadIdx.x;
    int n = gid >> 6, lane = gid & 63;
    if (n >= N) return;
    int beg = rowp[n], end = rowp[n + 1];
    float adn = adst[n];
    float mx = -1e30f;
    for (int i = beg + lane; i < end; i += 64) {
        int s = csr[i];
        mx = fmaxf(mx, lrelu(asrc[s] + adn));
    }
    #pragma unroll
    for (int off = 32; off; off >>= 1) mx = fmaxf(mx, __shfl_xor(mx, off));
    float acc0 = 0.f, acc1 = 0.f, acc2 = 0.f, acc3 = 0.f, den = 0.f;
    for (int i = beg; i < end; ++i) {
        int s = csr[i];
        float w = __expf(lrelu(asrc[s] + adn) - mx);
        den += w;
        const u16* hs = h1 + (size_t)s * 256;
        acc0 += w * bf2f(hs[lane]);
        acc1 += w * bf2f(hs[64 + lane]);
        acc2 += w * bf2f(hs[128 + lane]);
        acc3 += w * bf2f(hs[192 + lane]);
    }
    float inv = 1.f / den;
    u16* po = outx + (size_t)n * 256;
    float v;
    v = acc0 * inv + b[lane];       po[lane]       = f2bf(v > 0.f ? v : 0.f);
    v = acc1 * inv + b[64 + lane];  po[64 + lane]  = f2bf(v > 0.f ? v : 0.f);
    v = acc2 * inv + b[128 + lane]; po[128 + lane] = f2bf(v > 0.f ? v : 0.f);
    v = acc3 * inv + b[192 + lane]; po[192 + lane] = f2bf(v > 0.f ? v : 0.f);
}

// ---------------- weight packing: fp32 [K,Nsrc] -> bf16 MFMA B-fragments ----------------
__global__ void pack_w(const float* __restrict__ W, u16* __restrict__ out,
                       int K, int Nsrc, int NT) {
    int gid  = blockIdx.x * blockDim.x + threadIdx.x;
    int lane = gid & 63, frag = gid >> 6;
    int KT = K >> 5;
    if (frag >= KT * NT) return;
    int nt = frag % NT, kt = frag / NT;
    int n  = nt * 16 + (lane & 15);
    int k0 = kt * 32 + ((lane >> 4) << 3);
    u16x8 v8;
    #pragma unroll
    for (int i = 0; i < 8; ++i) {
        float v = (n < Nsrc) ? W[(size_t)(k0 + i) * Nsrc + n] : 0.f;
        v8[i] = f2bf(v);
    }
    *(u16x8*)(out + (size_t)(frag * 64 + lane) * 8) = v8;
}

// hi/lo split variant (for fp32-accurate GAT GEMMs)
__global__ void pack_w_hl(const float* __restrict__ W, u16* __restrict__ ohi,
                          u16* __restrict__ olo, int K, int Nsrc, int NT) {
    int gid  = blockIdx.x * blockDim.x + threadIdx.x;
    int lane = gid & 63, frag = gid >> 6;
    int KT = K >> 5;
    if (frag >= KT * NT) return;
    int nt = frag % NT, kt = frag / NT;
    int n  = nt * 16 + (lane & 15);
    int k0 = kt * 32 + ((lane >> 4) << 3);
    u16x8 h8, l8;
    #pragma unroll
    for (int i = 0; i < 8; ++i) {
        float v = (n < Nsrc) ? W[(size_t)(k0 + i) * Nsrc + n] : 0.f;
        u16 hi = f2bf(v);
        h8[i] = hi;
        l8[i] = f2bf(v - bf2f(hi));
    }
    *(u16x8*)(ohi + (size_t)(frag * 64 + lane) * 8) = h8;
    *(u16x8*)(olo + (size_t)(frag * 64 + lane) * 8) = l8;
}

// ---------------- shared A-fragment reader (XOR-swizzled LDS) ----------------
__device__ __forceinline__ bf16x8 lds_afrag(const u16* buf, int Kdim, int row0, int kt, int lane) {
    int row = row0 + (lane & 15);
    int k   = kt * 32 + ((lane >> 4) << 3);
    int idx = (row * Kdim + k) ^ ((row & 7) << 3);
    return *(const bf16x8*)(buf + idx);
}

// ---------------- split-bf16 MFMA GEMM: C[M,256] = A[M,K] @ B[K,256], fp32-accurate ----
// Output written as bf16 (feeds alphas + gathers, which read bf16).
__global__ __launch_bounds__(512) void gemm_mfma(
    const float* __restrict__ A, const u16* __restrict__ bhi, const u16* __restrict__ blo,
    u16* __restrict__ C, int M, int K) {
    __shared__ __align__(16) u16 Ahi[64 * 256];
    __shared__ __align__(16) u16 Alo[64 * 256];
    int t = threadIdx.x, lane = t & 63, w = t >> 6;
    int row0 = blockIdx.x * 64;
    int K4 = K >> 2;

    for (int idx = t; idx < 64 * K4; idx += 512) {
        int row = idx / K4, kq = (idx % K4) << 2;
        int gr = row0 + row;
        float4 v = make_float4(0.f, 0.f, 0.f, 0.f);
        if (gr < M) v = *(const float4*)(A + (size_t)gr * K + kq);
        u16x4 h4, l4;
        float vv[4] = {v.x, v.y, v.z, v.w};
        #pragma unroll
        for (int i = 0; i < 4; ++i) {
            u16 hi = f2bf(vv[i]);
            h4[i] = hi;
            l4[i] = f2bf(vv[i] - bf2f(hi));
        }
        int sidx = (row * K + kq) ^ ((row & 7) << 3);
        *(u16x4*)(Ahi + sidx) = h4;
        *(u16x4*)(Alo + sidx) = l4;
    }
    __syncthreads();

    int KT = K >> 5;
    f32x4 acc[4][2] = {};
    for (int kt = 0; kt < KT; ++kt) {
        bf16x8 ah[4], al[4];
        #pragma unroll
        for (int mt = 0; mt < 4; ++mt) {
            ah[mt] = lds_afrag(Ahi, K, mt * 16, kt, lane);
            al[mt] = lds_afrag(Alo, K, mt * 16, kt, lane);
        }
        #pragma unroll
        for (int nt = 0; nt < 2; ++nt) {
            int ntg = w * 2 + nt;
            size_t fo = ((size_t)(kt * 16 + ntg) * 64 + lane) * 8;
            bf16x8 bh = *(const bf16x8*)(bhi + fo);
            bf16x8 bl = *(const bf16x8*)(blo + fo);
            #pragma unroll
            for (int mt = 0; mt < 4; ++mt) {
                acc[mt][nt] = __builtin_amdgcn_mfma_f32_16x16x32_bf16(al[mt], bh, acc[mt][nt], 0, 0, 0);
                acc[mt][nt] = __builtin_amdgcn_mfma_f32_16x16x32_bf16(ah[mt], bl, acc[mt][nt], 0, 0, 0);
                acc[mt][nt] = __builtin_amdgcn_mfma_f32_16x16x32_bf16(ah[mt], bh, acc[mt][nt], 0, 0, 0);
            }
        }
    }

    #pragma unroll
    for (int mt = 0; mt < 4; ++mt)
        #pragma unroll
        for (int nt = 0; nt < 2; ++nt) {
            int col = w * 32 + nt * 16 + (lane & 15);
            #pragma unroll
            for (int j = 0; j < 4; ++j) {
                int gr = row0 + mt * 16 + ((lane >> 4) << 2) + j;
                if (gr < M) C[(size_t)gr * 256 + col] = f2bf(acc[mt][nt][j]);
            }
        }
}

// ---------------- fused MLP via bf16 MFMA: 256 -> 512 -> 1024 -> 10 -> softmax ----------------
// OCCUPANCY TEST: 32 rows/block, 512 threads, **50 KB LDS** (ldsIn 16 KB reused
// for input AND layer-2 chunk output; ldsA1 32 KB; slog 2 KB). Evidence from
// R4/R7/R9: usable-for-occupancy LDS appears to be ~128 KB, so 66-116 KB
// variants all ran 1 block/CU. 50 KB guarantees >=2 blocks/CU (3 if 160 usable)
// -> cross-block overlap of barriers + weight-load latency, per-block weight
// traffic unchanged. Layer 2 in 4 chunks of 256 cols, layer-3 partials in regs.
#define NB 32

__global__ __launch_bounds__(512) void mlp_mfma(
    const u16* __restrict__ m0,
    const u16* __restrict__ w1p, const float* __restrict__ lb1,
    const u16* __restrict__ w2p, const float* __restrict__ lb2,
    const u16* __restrict__ w3p, const float* __restrict__ lb3,
    float* __restrict__ out, int N) {
    __shared__ __align__(16) u16 ldsIn[32 * 256];   // 16 KB: input, then L2-chunk out
    __shared__ __align__(16) u16 ldsA1[32 * 512];   // 32 KB: layer-1 output
    __shared__ float slog[32 * 16];                  // 2 KB

    int t = threadIdx.x, lane = t & 63, w = t >> 6;
    int nb = blockIdx.x * NB;

    slog[t] = 0.f;

    // stage input tile -> ldsIn (swizzled, Kdim=256)
    #pragma unroll
    for (int u = 0; u < 2; ++u) {
        int unit = t + u * 512;
        int row = unit >> 5, kb = (unit & 31) << 3;
        int gn = nb + row;
        u16x8 v8;
        if (gn < N) v8 = *(const u16x8*)(m0 + (size_t)gn * 256 + kb);
        else        v8 = (u16x8)0;
        int idx = (row * 256 + kb) ^ ((row & 7) << 3);
        *(u16x8*)(ldsIn + idx) = v8;
    }
    __syncthreads();

    // ---- layer 1: [32,256] @ [256,512]; wave w owns cols [64w, 64w+64) ----
    {
        f32x4 acc1[2][4] = {};
        for (int kt = 0; kt < 8; ++kt) {
            bf16x8 a0 = lds_afrag(ldsIn, 256, 0,  kt, lane);
            bf16x8 a1 = lds_afrag(ldsIn, 256, 16, kt, lane);
            #pragma unroll
            for (int nt = 0; nt < 4; ++nt) {
                int ntg = w * 4 + nt;
                bf16x8 b = *(const bf16x8*)(w1p + ((size_t)(kt * 32 + ntg) * 64 + lane) * 8);
                acc1[0][nt] = __builtin_amdgcn_mfma_f32_16x16x32_bf16(a0, b, acc1[0][nt], 0, 0, 0);
                acc1[1][nt] = __builtin_amdgcn_mfma_f32_16x16x32_bf16(a1, b, acc1[1][nt], 0, 0, 0);
            }
        }
        // writeback (bias+relu) -> ldsA1
        #pragma unroll
        for (int mt = 0; mt < 2; ++mt)
            #pragma unroll
            for (int nt = 0; nt < 4; ++nt) {
                int col = w * 64 + nt * 16 + (lane & 15);
                float bv = lb1[col];
                #pragma unroll
                for (int j = 0; j < 4; ++j) {
                    int row = mt * 16 + ((lane >> 4) << 2) + j;
                    float v = acc1[mt][nt][j] + bv;
                    v = v > 0.f ? v : 0.f;
                    ldsA1[(row * 512 + col) ^ ((row & 7) << 3)] = f2bf(v);
                }
            }
    }
    __syncthreads();   // ldsA1 visible; all ldsIn reads complete -> ldsIn reusable

    // ---- layer 2 in 4 chunks of 256 cols + fused layer-3 K-partials ----
    // preload layer-3 B-fragments (global k-tile = ch*8 + w)
    bf16x8 b3[4];
    #pragma unroll
    for (int ch = 0; ch < 4; ++ch)
        b3[ch] = *(const bf16x8*)(w3p + ((size_t)(ch * 8 + w) * 64 + lane) * 8);

    f32x4 acc3[2] = {};
    for (int ch = 0; ch < 4; ++ch) {
        f32x4 acc[2][2] = {};
        for (int kt = 0; kt < 16; ++kt) {
            bf16x8 a0 = lds_afrag(ldsA1, 512, 0,  kt, lane);
            bf16x8 a1 = lds_afrag(ldsA1, 512, 16, kt, lane);
            #pragma unroll
            for (int nt = 0; nt < 2; ++nt) {
                int ntg = ch * 16 + w * 2 + nt;
                bf16x8 b = *(const bf16x8*)(w2p + ((size_t)(kt * 64 + ntg) * 64 + lane) * 8);
                acc[0][nt] = __builtin_amdgcn_mfma_f32_16x16x32_bf16(a0, b, acc[0][nt], 0, 0, 0);
                acc[1][nt] = __builtin_amdgcn_mfma_f32_16x16x32_bf16(a1, b, acc[1][nt], 0, 0, 0);
            }
        }
        // writeback chunk (bias+relu) -> ldsIn as [32][256] swizzled
        #pragma unroll
        for (int mt = 0; mt < 2; ++mt)
            #pragma unroll
            for (int nt = 0; nt < 2; ++nt) {
                int lcol = w * 32 + nt * 16 + (lane & 15);
                float bv = lb2[ch * 256 + lcol];
                #pragma unroll
                for (int j = 0; j < 4; ++j) {
                    int row = mt * 16 + ((lane >> 4) << 2) + j;
                    float v = acc[mt][nt][j] + bv;
                    v = v > 0.f ? v : 0.f;
                    ldsIn[(row * 256 + lcol) ^ ((row & 7) << 3)] = f2bf(v);
                }
            }
        __syncthreads();
        // layer-3 partial on this chunk: K=256 -> 8 k-tiles; wave w takes tile w
        {
            bf16x8 a0 = lds_afrag(ldsIn, 256, 0,  w, lane);
            bf16x8 a1 = lds_afrag(ldsIn, 256, 16, w, lane);
            acc3[0] = __builtin_amdgcn_mfma_f32_16x16x32_bf16(a0, b3[ch], acc3[0], 0, 0, 0);
            acc3[1] = __builtin_amdgcn_mfma_f32_16x16x32_bf16(a1, b3[ch], acc3[1], 0, 0, 0);
        }
        __syncthreads();   // chunk reads done before next chunk overwrites ldsIn
    }

    // reduce layer-3 partials across waves
    {
        int col = lane & 15;
        #pragma unroll
        for (int mt = 0; mt < 2; ++mt)
            #pragma unroll
            for (int j = 0; j < 4; ++j) {
                int row = mt * 16 + ((lane >> 4) << 2) + j;
                atomicAdd(&slog[row * 16 + col], acc3[mt][j]);
            }
    }
    __syncthreads();

    // ---- bias + relu + softmax ----
    if (t < 32) {
        int gn = nb + t;
        if (gn < N) {
            float lg[10], m = -1e30f;
            #pragma unroll
            for (int k = 0; k < 10; ++k) {
                float v = slog[t * 16 + k] + lb3[k];
                v = v > 0.f ? v : 0.f;
                lg[k] = v;
                if (v > m) m = v;
            }
            float ssum = 0.f;
            #pragma unroll
            for (int k = 0; k < 10; ++k) { lg[k] = __expf(lg[k] - m); ssum += lg[k]; }
            float inv = 1.f / ssum;
            #pragma unroll
            for (int k = 0; k < 10; ++k) out[(size_t)gn * 10 + k] = lg[k] * inv;
        }
    }
}

// ---------------------------------------------------------------------------
extern "C" void kernel_launch(void* const* d_in, const int* in_sizes, int n_in,
                              void* d_out, int out_size, void* d_ws, size_t ws_size,
                              hipStream_t stream) {
    const float* x       = (const float*)d_in[0];
    const int*   ei      = (const int*)  d_in[1];
    const float* W0      = (const float*)d_in[2];
    const float* a_src0  = (const float*)d_in[3];
    const float* a_dst0  = (const float*)d_in[4];
    const float* b0      = (const float*)d_in[5];
    const float* W1      = (const float*)d_in[6];
    const float* a_src1  = (const float*)d_in[7];
    const float* a_dst1  = (const float*)d_in[8];
    const float* b1      = (const float*)d_in[9];
    const float* lw1     = (const float*)d_in[10];
    const float* lb1     = (const float*)d_in[11];
    const float* lw2     = (const float*)d_in[12];
    const float* lb2     = (const float*)d_in[13];
    const float* lw3     = (const float*)d_in[14];
    const float* lb3     = (const float*)d_in[15];
    float*       out     = (float*)d_out;

    const int N  = in_sizes[0] / F_IN;   // 50000
    const int E  = in_sizes[1] / 2;      // 400000
    const int ET = E + N;

    // workspace layout (byte-based)
    char* base = (char*)d_ws;
    size_t szHb = (size_t)N * 256 * sizeof(u16);    // 25.6 MB
    u16*   hbf  = (u16*)base;                        // h0 / h1 (bf16)
    float* bufG = (float*)(base + szHb);             // x1 (fp32, feeds gemm hi/lo)
    u16*   m0b  = (u16*)(base + szHb + (size_t)N * 256 * sizeof(float));  // m0 (bf16)
    float* asrc = (float*)(base + 2 * szHb + (size_t)N * 256 * sizeof(float));
    float* adst = asrc + (size_t)N * 4;
    u16*   w1p  = (u16*)(adst + (size_t)N * 4);          // 256*512
    u16*   w2p  = w1p + 256 * 512;                       // 512*1024
    u16*   w3p  = w2p + 512 * 1024;                      // 1024*16
    u16*   w0h  = w3p + 1024 * 16;                       // 128*256 hi
    u16*   w0l  = w0h + 128 * 256;                       // 128*256 lo
    u16*   w1h  = w0l + 128 * 256;                       // 256*256 hi
    u16*   w1l  = w1h + 256 * 256;                       // 256*256 lo
    int*   deg  = (int*)(w1l + 256 * 256);
    int*   rowp   = deg + N;                  // N+1
    int*   cursor = rowp + N + 1;
    int*   part   = cursor + N;
    int*   bsum   = part + N;                 // 256
    int*   csr    = bsum + 256;               // ET

    const int TB  = 256;
    const int nb1 = (N + 255) / 256;
    const int gemm_grid = (N + 63) / 64;

    // ===== pack weights =====
    pack_w<<<(8  * 32 * 64 + TB - 1) / TB, TB, 0, stream>>>(lw1, w1p, 256,  512,  32);
    pack_w<<<(16 * 64 * 64 + TB - 1) / TB, TB, 0, stream>>>(lw2, w2p, 512,  1024, 64);
    pack_w<<<(32 * 1  * 64 + TB - 1) / TB, TB, 0, stream>>>(lw3, w3p, 1024, 10,   1);
    pack_w_hl<<<(4 * 16 * 64 + TB - 1) / TB, TB, 0, stream>>>(W0, w0h, w0l, 128, 256, 16);
    pack_w_hl<<<(8 * 16 * 64 + TB - 1) / TB, TB, 0, stream>>>(W1, w1h, w1l, 256, 256, 16);

    // ===== build CSR (dst-sorted; valid edges + self-loops) =====
    deg_init<<<nb1, TB, 0, stream>>>(deg, N);
    count_deg<<<(E + TB - 1) / TB, TB, 0, stream>>>(ei, deg, E);
    scan1<<<nb1, TB, 0, stream>>>(deg, part, bsum, N);
    scan2<<<1, TB, 0, stream>>>(bsum, nb1);
    scan3<<<nb1, TB, 0, stream>>>(deg, part, bsum, rowp, cursor, N);
    scatter_k<<<(ET + TB - 1) / TB, TB, 0, stream>>>(ei, cursor, csr, E, N);

    // ===== GAT layer 0 =====
    gemm_mfma<<<gemm_grid, 512, 0, stream>>>(x, w0h, w0l, hbf, N, 128);
    alphas0_k<<<(N * 64 + TB - 1) / TB, TB, 0, stream>>>(hbf, a_src0, a_dst0, asrc, adst, N);
    gat_gather0<<<((size_t)N * 64 + TB - 1) / TB, TB, 0, stream>>>(csr, rowp, hbf, asrc, adst, b0, bufG, N);

    // ===== GAT layer 1 =====
    gemm_mfma<<<gemm_grid, 512, 0, stream>>>(bufG, w1h, w1l, hbf, N, 256);
    alphas1_k<<<(N * 64 + TB - 1) / TB, TB, 0, stream>>>(hbf, a_src1, a_dst1, asrc, adst, N);
    gat_gather1<<<((size_t)N * 64 + TB - 1) / TB, TB, 0, stream>>>(csr, rowp, hbf, asrc, adst, b1, m0b, N);

    // ===== fused MLP head (bf16 MFMA) + softmax =====
    mlp_mfma<<<(N + NB - 1) / NB, 512, 0, stream>>>(m0b, w1p, lb1, w2p, lb2, w3p, lb3, out, N);
}

// Round 12
// 372.414 us; speedup vs baseline: 1.4285x; 1.4285x over previous
//
#include <hip/hip_runtime.h>
#include <cstdint>
#include <cstddef>

#define F_IN   128
#define SLOPE  0.2f

typedef unsigned short u16;
typedef __attribute__((ext_vector_type(8))) short     bf16x8;
typedef __attribute__((ext_vector_type(8))) unsigned short u16x8;
typedef __attribute__((ext_vector_type(4))) unsigned short u16x4;
typedef __attribute__((ext_vector_type(4))) float     f32x4;

// ---------- float -> bf16 (round-to-nearest-even) ----------
__device__ __forceinline__ u16 f2bf(float f) {
    unsigned u = __float_as_uint(f);
    unsigned r = u + 0x7FFFu + ((u >> 16) & 1u);
    return (u16)(r >> 16);
}
__device__ __forceinline__ float bf2f(u16 h) {
    return __uint_as_float(((unsigned)h) << 16);
}

__device__ __forceinline__ float lrelu(float v) { return v >= 0.f ? v : SLOPE * v; }

// ---------------- alpha dot products (bf16 h, u16x4 per lane) ----------------
__global__ void alphas0_k(const u16* __restrict__ h0, const float* __restrict__ a_src,
                          const float* __restrict__ a_dst, float* __restrict__ asrc,
                          float* __restrict__ adst, int N) {
    int gid = blockIdx.x * blockDim.x + threadIdx.x;
    int n = gid >> 6, lane = gid & 63;
    if (n >= N) return;
    int h = lane >> 4, c0 = lane << 2;
    u16x4 hv = *(const u16x4*)(h0 + (size_t)n * 256 + c0);
    float4 ws = *(const float4*)(a_src + c0);
    float4 wd = *(const float4*)(a_dst + c0);
    float s1 = bf2f(hv[0]) * ws.x + bf2f(hv[1]) * ws.y + bf2f(hv[2]) * ws.z + bf2f(hv[3]) * ws.w;
    float s2 = bf2f(hv[0]) * wd.x + bf2f(hv[1]) * wd.y + bf2f(hv[2]) * wd.z + bf2f(hv[3]) * wd.w;
    #pragma unroll
    for (int off = 8; off; off >>= 1) {
        s1 += __shfl_xor(s1, off);
        s2 += __shfl_xor(s2, off);
    }
    if ((lane & 15) == 0) { asrc[n * 4 + h] = s1; adst[n * 4 + h] = s2; }
}

__global__ void alphas1_k(const u16* __restrict__ h1, const float* __restrict__ a_src,
                          const float* __restrict__ a_dst, float* __restrict__ asrc,
                          float* __restrict__ adst, int N) {
    int gid = blockIdx.x * blockDim.x + threadIdx.x;
    int n = gid >> 6, lane = gid & 63;
    if (n >= N) return;
    int c0 = lane << 2;
    u16x4 hv = *(const u16x4*)(h1 + (size_t)n * 256 + c0);
    float4 ws = *(const float4*)(a_src + c0);
    float4 wd = *(const float4*)(a_dst + c0);
    float s1 = bf2f(hv[0]) * ws.x + bf2f(hv[1]) * ws.y + bf2f(hv[2]) * ws.z + bf2f(hv[3]) * ws.w;
    float s2 = bf2f(hv[0]) * wd.x + bf2f(hv[1]) * wd.y + bf2f(hv[2]) * wd.z + bf2f(hv[3]) * wd.w;
    #pragma unroll
    for (int off = 32; off; off >>= 1) {
        s1 += __shfl_xor(s1, off);
        s2 += __shfl_xor(s2, off);
    }
    if (lane == 0) { asrc[n] = s1; adst[n] = s2; }
}

// ---------------- CSR build (by destination; valid edges + self-loops) ----------------
__global__ void deg_init(int* __restrict__ deg, int N) {
    int i = blockIdx.x * blockDim.x + threadIdx.x;
    if (i < N) deg[i] = 1;                      // self-loop
}

__global__ void count_deg(const int* __restrict__ ei, int* __restrict__ deg, int E) {
    int e = blockIdx.x * blockDim.x + threadIdx.x;
    if (e >= E) return;
    int s = ei[e], d = ei[E + e];
    if (s != d) atomicAdd(&deg[d], 1);
}

__global__ void scan1(const int* __restrict__ deg, int* __restrict__ part,
                      int* __restrict__ bsum, int N) {
    __shared__ int sm[256];
    int i = blockIdx.x * 256 + threadIdx.x;
    int v = (i < N) ? deg[i] : 0;
    sm[threadIdx.x] = v; __syncthreads();
    for (int off = 1; off < 256; off <<= 1) {
        int tv = (threadIdx.x >= off) ? sm[threadIdx.x - off] : 0;
        __syncthreads();
        sm[threadIdx.x] += tv;
        __syncthreads();
    }
    if (i < N) part[i] = sm[threadIdx.x] - v;   // exclusive within block
    if (threadIdx.x == 255) bsum[blockIdx.x] = sm[255];
}

__global__ void scan2(int* __restrict__ bsum, int nb) {
    __shared__ int sm[256];
    __shared__ int carry;
    if (threadIdx.x == 0) carry = 0;
    __syncthreads();
    for (int base = 0; base < nb; base += 256) {
        int i = base + threadIdx.x;
        int v = (i < nb) ? bsum[i] : 0;
        sm[threadIdx.x] = v; __syncthreads();
        for (int off = 1; off < 256; off <<= 1) {
            int tv = (threadIdx.x >= off) ? sm[threadIdx.x - off] : 0;
            __syncthreads();
            sm[threadIdx.x] += tv;
            __syncthreads();
        }
        if (i < nb) bsum[i] = sm[threadIdx.x] - v + carry;
        __syncthreads();
        if (threadIdx.x == 0) carry += sm[255];
        __syncthreads();
    }
}

__global__ void scan3(const int* __restrict__ deg, const int* __restrict__ part,
                      const int* __restrict__ bsum, int* __restrict__ rowp,
                      int* __restrict__ cursor, int N) {
    int i = blockIdx.x * blockDim.x + threadIdx.x;
    if (i >= N) return;
    int r = part[i] + bsum[i >> 8];
    rowp[i] = r;
    cursor[i] = r;
    if (i == N - 1) rowp[N] = r + deg[i];
}

__global__ void scatter_k(const int* __restrict__ ei, int* __restrict__ cursor,
                          int* __restrict__ csr, int E, int N) {
    int e = blockIdx.x * blockDim.x + threadIdx.x;
    if (e >= E + N) return;
    int s, d;
    if (e < E) { s = ei[e]; d = ei[E + e]; if (s == d) return; }
    else       { s = d = e - E; }
    int pos = atomicAdd(&cursor[d], 1);
    csr[pos] = s;
}

// ---------------- GAT gather-aggregate (vectorized: lane owns 4 channels) ----------------
// layer0: head h = lane>>4; one u16x4 load + one exp per edge per lane.
__global__ void gat_gather0(const int* __restrict__ csr, const int* __restrict__ rowp,
                            const u16* __restrict__ h0, const float* __restrict__ asrc,
                            const float* __restrict__ adst, const float* __restrict__ b,
                            float* __restrict__ outx, int N) {
    int gid = blockIdx.x * blockDim.x + threadIdx.x;
    int n = gid >> 6, lane = gid & 63;
    if (n >= N) return;
    int h = lane >> 4, c0 = lane << 2;
    int beg = rowp[n], end = rowp[n + 1];
    float4 ad = *(const float4*)(adst + (size_t)n * 4);
    // pass 1: per-head max — every lane scores all 4 heads (full edge coverage)
    float m0 = -1e30f, m1 = -1e30f, m2 = -1e30f, m3 = -1e30f;
    for (int i = beg + lane; i < end; i += 64) {
        int s = csr[i];
        float4 as = *(const float4*)(asrc + (size_t)s * 4);
        m0 = fmaxf(m0, lrelu(as.x + ad.x));
        m1 = fmaxf(m1, lrelu(as.y + ad.y));
        m2 = fmaxf(m2, lrelu(as.z + ad.z));
        m3 = fmaxf(m3, lrelu(as.w + ad.w));
    }
    #pragma unroll
    for (int off = 32; off; off >>= 1) {
        m0 = fmaxf(m0, __shfl_xor(m0, off));
        m1 = fmaxf(m1, __shfl_xor(m1, off));
        m2 = fmaxf(m2, __shfl_xor(m2, off));
        m3 = fmaxf(m3, __shfl_xor(m3, off));
    }
    float mh  = (h == 0) ? m0   : (h == 1) ? m1   : (h == 2) ? m2   : m3;
    float adh = (h == 0) ? ad.x : (h == 1) ? ad.y : (h == 2) ? ad.z : ad.w;
    // pass 2: weighted gather; den identical across a head's 16 lanes (no reduce)
    float acc0 = 0.f, acc1 = 0.f, acc2 = 0.f, acc3 = 0.f, den = 0.f;
    #pragma unroll 2
    for (int i = beg; i < end; ++i) {
        int s = csr[i];
        float w = __expf(lrelu(asrc[(size_t)s * 4 + h] + adh) - mh);
        den += w;
        u16x4 hv = *(const u16x4*)(h0 + (size_t)s * 256 + c0);
        acc0 += w * bf2f(hv[0]);
        acc1 += w * bf2f(hv[1]);
        acc2 += w * bf2f(hv[2]);
        acc3 += w * bf2f(hv[3]);
    }
    float inv = 1.f / den;
    float4 bb = *(const float4*)(b + c0);
    float4 ov;
    ov.x = acc0 * inv + bb.x; ov.x = ov.x > 0.f ? ov.x : 0.f;
    ov.y = acc1 * inv + bb.y; ov.y = ov.y > 0.f ? ov.y : 0.f;
    ov.z = acc2 * inv + bb.z; ov.z = ov.z > 0.f ? ov.z : 0.f;
    ov.w = acc3 * inv + bb.w; ov.w = ov.w > 0.f ? ov.w : 0.f;
    *(float4*)(outx + (size_t)n * 256 + c0) = ov;
}

// layer1: single head; writes m0 directly as bf16 u16x4.
__global__ void gat_gather1(const int* __restrict__ csr, const int* __restrict__ rowp,
                            const u16* __restrict__ h1, const float* __restrict__ asrc,
                            const float* __restrict__ adst, const float* __restrict__ b,
                            u16* __restrict__ outx, int N) {
    int gid = blockIdx.x * blockDim.x + threadIdx.x;
    int n = gid >> 6, lane = gid & 63;
    if (n >= N) return;
    int c0 = lane << 2;
    int beg = rowp[n], end = rowp[n + 1];
    float adn = adst[n];
    float mx = -1e30f;
    for (int i = beg + lane; i < end; i += 64) {
        int s = csr[i];
        mx = fmaxf(mx, lrelu(asrc[s] + adn));
    }
    #pragma unroll
    for (int off = 32; off; off >>= 1) mx = fmaxf(mx, __shfl_xor(mx, off));
    float acc0 = 0.f, acc1 = 0.f, acc2 = 0.f, acc3 = 0.f, den = 0.f;
    #pragma unroll 2
    for (int i = beg; i < end; ++i) {
        int s = csr[i];
        float w = __expf(lrelu(asrc[s] + adn) - mx);
        den += w;
        u16x4 hv = *(const u16x4*)(h1 + (size_t)s * 256 + c0);
        acc0 += w * bf2f(hv[0]);
        acc1 += w * bf2f(hv[1]);
        acc2 += w * bf2f(hv[2]);
        acc3 += w * bf2f(hv[3]);
    }
    float inv = 1.f / den;
    float4 bb = *(const float4*)(b + c0);
    float v0 = acc0 * inv + bb.x, v1 = acc1 * inv + bb.y;
    float v2 = acc2 * inv + bb.z, v3 = acc3 * inv + bb.w;
    u16x4 ov;
    ov[0] = f2bf(v0 > 0.f ? v0 : 0.f);
    ov[1] = f2bf(v1 > 0.f ? v1 : 0.f);
    ov[2] = f2bf(v2 > 0.f ? v2 : 0.f);
    ov[3] = f2bf(v3 > 0.f ? v3 : 0.f);
    *(u16x4*)(outx + (size_t)n * 256 + c0) = ov;
}

// ---------------- weight packing: fp32 [K,Nsrc] -> bf16 MFMA B-fragments ----------------
__global__ void pack_w(const float* __restrict__ W, u16* __restrict__ out,
                       int K, int Nsrc, int NT) {
    int gid  = blockIdx.x * blockDim.x + threadIdx.x;
    int lane = gid & 63, frag = gid >> 6;
    int KT = K >> 5;
    if (frag >= KT * NT) return;
    int nt = frag % NT, kt = frag / NT;
    int n  = nt * 16 + (lane & 15);
    int k0 = kt * 32 + ((lane >> 4) << 3);
    u16x8 v8;
    #pragma unroll
    for (int i = 0; i < 8; ++i) {
        float v = (n < Nsrc) ? W[(size_t)(k0 + i) * Nsrc + n] : 0.f;
        v8[i] = f2bf(v);
    }
    *(u16x8*)(out + (size_t)(frag * 64 + lane) * 8) = v8;
}

// hi/lo split variant (for fp32-accurate GAT GEMMs)
__global__ void pack_w_hl(const float* __restrict__ W, u16* __restrict__ ohi,
                          u16* __restrict__ olo, int K, int Nsrc, int NT) {
    int gid  = blockIdx.x * blockDim.x + threadIdx.x;
    int lane = gid & 63, frag = gid >> 6;
    int KT = K >> 5;
    if (frag >= KT * NT) return;
    int nt = frag % NT, kt = frag / NT;
    int n  = nt * 16 + (lane & 15);
    int k0 = kt * 32 + ((lane >> 4) << 3);
    u16x8 h8, l8;
    #pragma unroll
    for (int i = 0; i < 8; ++i) {
        float v = (n < Nsrc) ? W[(size_t)(k0 + i) * Nsrc + n] : 0.f;
        u16 hi = f2bf(v);
        h8[i] = hi;
        l8[i] = f2bf(v - bf2f(hi));
    }
    *(u16x8*)(ohi + (size_t)(frag * 64 + lane) * 8) = h8;
    *(u16x8*)(olo + (size_t)(frag * 64 + lane) * 8) = l8;
}

// ---------------- shared A-fragment reader (XOR-swizzled LDS) ----------------
__device__ __forceinline__ bf16x8 lds_afrag(const u16* buf, int Kdim, int row0, int kt, int lane) {
    int row = row0 + (lane & 15);
    int k   = kt * 32 + ((lane >> 4) << 3);
    int idx = (row * Kdim + k) ^ ((row & 7) << 3);
    return *(const bf16x8*)(buf + idx);
}

// ---------------- split-bf16 MFMA GEMM: C[M,256] = A[M,K] @ B[K,256], fp32-accurate ----
__global__ __launch_bounds__(512) void gemm_mfma(
    const float* __restrict__ A, const u16* __restrict__ bhi, const u16* __restrict__ blo,
    u16* __restrict__ C, int M, int K) {
    __shared__ __align__(16) u16 Ahi[64 * 256];
    __shared__ __align__(16) u16 Alo[64 * 256];
    int t = threadIdx.x, lane = t & 63, w = t >> 6;
    int row0 = blockIdx.x * 64;
    int K4 = K >> 2;

    for (int idx = t; idx < 64 * K4; idx += 512) {
        int row = idx / K4, kq = (idx % K4) << 2;
        int gr = row0 + row;
        float4 v = make_float4(0.f, 0.f, 0.f, 0.f);
        if (gr < M) v = *(const float4*)(A + (size_t)gr * K + kq);
        u16x4 h4, l4;
        float vv[4] = {v.x, v.y, v.z, v.w};
        #pragma unroll
        for (int i = 0; i < 4; ++i) {
            u16 hi = f2bf(vv[i]);
            h4[i] = hi;
            l4[i] = f2bf(vv[i] - bf2f(hi));
        }
        int sidx = (row * K + kq) ^ ((row & 7) << 3);
        *(u16x4*)(Ahi + sidx) = h4;
        *(u16x4*)(Alo + sidx) = l4;
    }
    __syncthreads();

    int KT = K >> 5;
    f32x4 acc[4][2] = {};
    for (int kt = 0; kt < KT; ++kt) {
        bf16x8 ah[4], al[4];
        #pragma unroll
        for (int mt = 0; mt < 4; ++mt) {
            ah[mt] = lds_afrag(Ahi, K, mt * 16, kt, lane);
            al[mt] = lds_afrag(Alo, K, mt * 16, kt, lane);
        }
        #pragma unroll
        for (int nt = 0; nt < 2; ++nt) {
            int ntg = w * 2 + nt;
            size_t fo = ((size_t)(kt * 16 + ntg) * 64 + lane) * 8;
            bf16x8 bh = *(const bf16x8*)(bhi + fo);
            bf16x8 bl = *(const bf16x8*)(blo + fo);
            #pragma unroll
            for (int mt = 0; mt < 4; ++mt) {
                acc[mt][nt] = __builtin_amdgcn_mfma_f32_16x16x32_bf16(al[mt], bh, acc[mt][nt], 0, 0, 0);
                acc[mt][nt] = __builtin_amdgcn_mfma_f32_16x16x32_bf16(ah[mt], bl, acc[mt][nt], 0, 0, 0);
                acc[mt][nt] = __builtin_amdgcn_mfma_f32_16x16x32_bf16(ah[mt], bh, acc[mt][nt], 0, 0, 0);
            }
        }
    }

    #pragma unroll
    for (int mt = 0; mt < 4; ++mt)
        #pragma unroll
        for (int nt = 0; nt < 2; ++nt) {
            int col = w * 32 + nt * 16 + (lane & 15);
            #pragma unroll
            for (int j = 0; j < 4; ++j) {
                int gr = row0 + mt * 16 + ((lane >> 4) << 2) + j;
                if (gr < M) C[(size_t)gr * 256 + col] = f2bf(acc[mt][nt][j]);
            }
        }
}

// ---------------- fused MLP via bf16 MFMA (R9 structure, parked at ~158 us) ----------------
#define NB 32

__global__ __launch_bounds__(512) void mlp_mfma(
    const u16* __restrict__ m0,
    const u16* __restrict__ w1p, const float* __restrict__ lb1,
    const u16* __restrict__ w2p, const float* __restrict__ lb2,
    const u16* __restrict__ w3p, const float* __restrict__ lb3,
    float* __restrict__ out, int N) {
    __shared__ __align__(16) u16 ldsA0[32 * 256];    // 16 KB
    __shared__ __align__(16) u16 ldsA1[32 * 512];    // 32 KB
    __shared__ __align__(16) u16 ldsA2[32 * 1024];   // 64 KB
    __shared__ float slog[32 * 16];                   // 2 KB

    int t = threadIdx.x, lane = t & 63, w = t >> 6;
    int nb = blockIdx.x * NB;

    slog[t] = 0.f;

    // issue layer-1 kt=0 weight fragments immediately (fly during staging)
    bf16x8 b1A[4], b1B[4];
    #pragma unroll
    for (int nt = 0; nt < 4; ++nt)
        b1A[nt] = *(const bf16x8*)(w1p + ((size_t)(w * 4 + nt) * 64 + lane) * 8);

    // stage input tile -> LDS (swizzled), bf16 u16x8 loads
    #pragma unroll
    for (int u = 0; u < 2; ++u) {
        int unit = t + u * 512;
        int row = unit >> 5, kb = (unit & 31) << 3;
        int gn = nb + row;
        u16x8 v8;
        if (gn < N) v8 = *(const u16x8*)(m0 + (size_t)gn * 256 + kb);
        else        v8 = (u16x8)0;
        int idx = (row * 256 + kb) ^ ((row & 7) << 3);
        *(u16x8*)(ldsA0 + idx) = v8;
    }
    __syncthreads();

    // ---- layer 1: [32,256] @ [256,512]; wave w owns cols [64w, 64w+64) ----
    f32x4 acc1[2][4] = {};
    for (int kt = 0; kt < 8; kt += 2) {
        #pragma unroll
        for (int nt = 0; nt < 4; ++nt)
            b1B[nt] = *(const bf16x8*)(w1p + ((size_t)((kt + 1) * 32 + w * 4 + nt) * 64 + lane) * 8);
        {
            bf16x8 a0 = lds_afrag(ldsA0, 256, 0,  kt, lane);
            bf16x8 a1 = lds_afrag(ldsA0, 256, 16, kt, lane);
            #pragma unroll
            for (int nt = 0; nt < 4; ++nt) {
                acc1[0][nt] = __builtin_amdgcn_mfma_f32_16x16x32_bf16(a0, b1A[nt], acc1[0][nt], 0, 0, 0);
                acc1[1][nt] = __builtin_amdgcn_mfma_f32_16x16x32_bf16(a1, b1A[nt], acc1[1][nt], 0, 0, 0);
            }
        }
        if (kt + 2 < 8) {
            #pragma unroll
            for (int nt = 0; nt < 4; ++nt)
                b1A[nt] = *(const bf16x8*)(w1p + ((size_t)((kt + 2) * 32 + w * 4 + nt) * 64 + lane) * 8);
        }
        {
            bf16x8 a0 = lds_afrag(ldsA0, 256, 0,  kt + 1, lane);
            bf16x8 a1 = lds_afrag(ldsA0, 256, 16, kt + 1, lane);
            #pragma unroll
            for (int nt = 0; nt < 4; ++nt) {
                acc1[0][nt] = __builtin_amdgcn_mfma_f32_16x16x32_bf16(a0, b1B[nt], acc1[0][nt], 0, 0, 0);
                acc1[1][nt] = __builtin_amdgcn_mfma_f32_16x16x32_bf16(a1, b1B[nt], acc1[1][nt], 0, 0, 0);
            }
        }
    }

    // issue layer-2 kt=0 weight fragments BEFORE writeback+barrier
    bf16x8 b2A[8], b2B[8];
    #pragma unroll
    for (int nt = 0; nt < 8; ++nt)
        b2A[nt] = *(const bf16x8*)(w2p + ((size_t)(w * 8 + nt) * 64 + lane) * 8);

    // layer-1 writeback (bias+relu) -> ldsA1
    #pragma unroll
    for (int mt = 0; mt < 2; ++mt)
        #pragma unroll
        for (int nt = 0; nt < 4; ++nt) {
            int col = w * 64 + nt * 16 + (lane & 15);
            float bv = lb1[col];
            #pragma unroll
            for (int j = 0; j < 4; ++j) {
                int row = mt * 16 + ((lane >> 4) << 2) + j;
                float v = acc1[mt][nt][j] + bv;
                v = v > 0.f ? v : 0.f;
                ldsA1[(row * 512 + col) ^ ((row & 7) << 3)] = f2bf(v);
            }
        }
    __syncthreads();

    // ---- layer 2: [32,512] @ [512,1024]; wave w owns cols [128w, 128w+128) ----
    f32x4 acc2[2][8] = {};
    for (int kt = 0; kt < 16; kt += 2) {
        #pragma unroll
        for (int nt = 0; nt < 8; ++nt)
            b2B[nt] = *(const bf16x8*)(w2p + ((size_t)((kt + 1) * 64 + w * 8 + nt) * 64 + lane) * 8);
        {
            bf16x8 a0 = lds_afrag(ldsA1, 512, 0,  kt, lane);
            bf16x8 a1 = lds_afrag(ldsA1, 512, 16, kt, lane);
            #pragma unroll
            for (int nt = 0; nt < 8; ++nt) {
                acc2[0][nt] = __builtin_amdgcn_mfma_f32_16x16x32_bf16(a0, b2A[nt], acc2[0][nt], 0, 0, 0);
                acc2[1][nt] = __builtin_amdgcn_mfma_f32_16x16x32_bf16(a1, b2A[nt], acc2[1][nt], 0, 0, 0);
            }
        }
        if (kt + 2 < 16) {
            #pragma unroll
            for (int nt = 0; nt < 8; ++nt)
                b2A[nt] = *(const bf16x8*)(w2p + ((size_t)((kt + 2) * 64 + w * 8 + nt) * 64 + lane) * 8);
        }
        {
            bf16x8 a0 = lds_afrag(ldsA1, 512, 0,  kt + 1, lane);
            bf16x8 a1 = lds_afrag(ldsA1, 512, 16, kt + 1, lane);
            #pragma unroll
            for (int nt = 0; nt < 8; ++nt) {
                acc2[0][nt] = __builtin_amdgcn_mfma_f32_16x16x32_bf16(a0, b2B[nt], acc2[0][nt], 0, 0, 0);
                acc2[1][nt] = __builtin_amdgcn_mfma_f32_16x16x32_bf16(a1, b2B[nt], acc2[1][nt], 0, 0, 0);
            }
        }
    }

    // issue layer-3 weight fragments BEFORE writeback+barrier
    bf16x8 b3[4];
    #pragma unroll
    for (int kk = 0; kk < 4; ++kk)
        b3[kk] = *(const bf16x8*)(w3p + ((size_t)(w * 4 + kk) * 64 + lane) * 8);

    // layer-2 writeback (bias+relu) -> ldsA2
    #pragma unroll
    for (int mt = 0; mt < 2; ++mt)
        #pragma unroll
        for (int nt = 0; nt < 8; ++nt) {
            int col = w * 128 + nt * 16 + (lane & 15);
            float bv = lb2[col];
            #pragma unroll
            for (int j = 0; j < 4; ++j) {
                int row = mt * 16 + ((lane >> 4) << 2) + j;
                float v = acc2[mt][nt][j] + bv;
                v = v > 0.f ? v : 0.f;
                ldsA2[(row * 1024 + col) ^ ((row & 7) << 3)] = f2bf(v);
            }
        }
    __syncthreads();

    // ---- layer 3: [32,1024] @ [1024,16(10 valid)]; wave w owns kt = 4w..4w+3 ----
    {
        f32x4 acc[2] = {};
        #pragma unroll
        for (int kk = 0; kk < 4; ++kk) {
            int kt = w * 4 + kk;
            bf16x8 a0 = lds_afrag(ldsA2, 1024, 0,  kt, lane);
            bf16x8 a1 = lds_afrag(ldsA2, 1024, 16, kt, lane);
            acc[0] = __builtin_amdgcn_mfma_f32_16x16x32_bf16(a0, b3[kk], acc[0], 0, 0, 0);
            acc[1] = __builtin_amdgcn_mfma_f32_16x16x32_bf16(a1, b3[kk], acc[1], 0, 0, 0);
        }
        int col = lane & 15;
        #pragma unroll
        for (int mt = 0; mt < 2; ++mt)
            #pragma unroll
            for (int j = 0; j < 4; ++j) {
                int row = mt * 16 + ((lane >> 4) << 2) + j;
                atomicAdd(&slog[row * 16 + col], acc[mt][j]);
            }
    }
    __syncthreads();

    // ---- bias + relu + softmax ----
    if (t < 32) {
        int gn = nb + t;
        if (gn < N) {
            float lg[10], m = -1e30f;
            #pragma unroll
            for (int k = 0; k < 10; ++k) {
                float v = slog[t * 16 + k] + lb3[k];
                v = v > 0.f ? v : 0.f;
                lg[k] = v;
                if (v > m) m = v;
            }
            float ssum = 0.f;
            #pragma unroll
            for (int k = 0; k < 10; ++k) { lg[k] = __expf(lg[k] - m); ssum += lg[k]; }
            float inv = 1.f / ssum;
            #pragma unroll
            for (int k = 0; k < 10; ++k) out[(size_t)gn * 10 + k] = lg[k] * inv;
        }
    }
}

// ---------------------------------------------------------------------------
extern "C" void kernel_launch(void* const* d_in, const int* in_sizes, int n_in,
                              void* d_out, int out_size, void* d_ws, size_t ws_size,
                              hipStream_t stream) {
    const float* x       = (const float*)d_in[0];
    const int*   ei      = (const int*)  d_in[1];
    const float* W0      = (const float*)d_in[2];
    const float* a_src0  = (const float*)d_in[3];
    const float* a_dst0  = (const float*)d_in[4];
    const float* b0      = (const float*)d_in[5];
    const float* W1      = (const float*)d_in[6];
    const float* a_src1  = (const float*)d_in[7];
    const float* a_dst1  = (const float*)d_in[8];
    const float* b1      = (const float*)d_in[9];
    const float* lw1     = (const float*)d_in[10];
    const float* lb1     = (const float*)d_in[11];
    const float* lw2     = (const float*)d_in[12];
    const float* lb2     = (const float*)d_in[13];
    const float* lw3     = (const float*)d_in[14];
    const float* lb3     = (const float*)d_in[15];
    float*       out     = (float*)d_out;

    const int N  = in_sizes[0] / F_IN;   // 50000
    const int E  = in_sizes[1] / 2;      // 400000
    const int ET = E + N;

    // workspace layout (byte-based)
    char* base = (char*)d_ws;
    size_t szHb = (size_t)N * 256 * sizeof(u16);    // 25.6 MB
    u16*   hbf  = (u16*)base;                        // h0 / h1 (bf16)
    float* bufG = (float*)(base + szHb);             // x1 (fp32, feeds gemm hi/lo)
    u16*   m0b  = (u16*)(base + szHb + (size_t)N * 256 * sizeof(float));  // m0 (bf16)
    float* asrc = (float*)(base + 2 * szHb + (size_t)N * 256 * sizeof(float));
    float* adst = asrc + (size_t)N * 4;
    u16*   w1p  = (u16*)(adst + (size_t)N * 4);          // 256*512
    u16*   w2p  = w1p + 256 * 512;                       // 512*1024
    u16*   w3p  = w2p + 512 * 1024;                      // 1024*16
    u16*   w0h  = w3p + 1024 * 16;                       // 128*256 hi
    u16*   w0l  = w0h + 128 * 256;                       // 128*256 lo
    u16*   w1h  = w0l + 128 * 256;                       // 256*256 hi
    u16*   w1l  = w1h + 256 * 256;                       // 256*256 lo
    int*   deg  = (int*)(w1l + 256 * 256);
    int*   rowp   = deg + N;                  // N+1
    int*   cursor = rowp + N + 1;
    int*   part   = cursor + N;
    int*   bsum   = part + N;                 // 256
    int*   csr    = bsum + 256;               // ET

    const int TB  = 256;
    const int nb1 = (N + 255) / 256;
    const int gemm_grid = (N + 63) / 64;

    // ===== pack weights =====
    pack_w<<<(8  * 32 * 64 + TB - 1) / TB, TB, 0, stream>>>(lw1, w1p, 256,  512,  32);
    pack_w<<<(16 * 64 * 64 + TB - 1) / TB, TB, 0, stream>>>(lw2, w2p, 512,  1024, 64);
    pack_w<<<(32 * 1  * 64 + TB - 1) / TB, TB, 0, stream>>>(lw3, w3p, 1024, 10,   1);
    pack_w_hl<<<(4 * 16 * 64 + TB - 1) / TB, TB, 0, stream>>>(W0, w0h, w0l, 128, 256, 16);
    pack_w_hl<<<(8 * 16 * 64 + TB - 1) / TB, TB, 0, stream>>>(W1, w1h, w1l, 256, 256, 16);

    // ===== build CSR (dst-sorted; valid edges + self-loops) =====
    deg_init<<<nb1, TB, 0, stream>>>(deg, N);
    count_deg<<<(E + TB - 1) / TB, TB, 0, stream>>>(ei, deg, E);
    scan1<<<nb1, TB, 0, stream>>>(deg, part, bsum, N);
    scan2<<<1, TB, 0, stream>>>(bsum, nb1);
    scan3<<<nb1, TB, 0, stream>>>(deg, part, bsum, rowp, cursor, N);
    scatter_k<<<(ET + TB - 1) / TB, TB, 0, stream>>>(ei, cursor, csr, E, N);

    // ===== GAT layer 0 =====
    gemm_mfma<<<gemm_grid, 512, 0, stream>>>(x, w0h, w0l, hbf, N, 128);
    alphas0_k<<<(N * 64 + TB - 1) / TB, TB, 0, stream>>>(hbf, a_src0, a_dst0, asrc, adst, N);
    gat_gather0<<<((size_t)N * 64 + TB - 1) / TB, TB, 0, stream>>>(csr, rowp, hbf, asrc, adst, b0, bufG, N);

    // ===== GAT layer 1 =====
    gemm_mfma<<<gemm_grid, 512, 0, stream>>>(bufG, w1h, w1l, hbf, N, 256);
    alphas1_k<<<(N * 64 + TB - 1) / TB, TB, 0, stream>>>(hbf, a_src1, a_dst1, asrc, adst, N);
    gat_gather1<<<((size_t)N * 64 + TB - 1) / TB, TB, 0, stream>>>(csr, rowp, hbf, asrc, adst, b1, m0b, N);

    // ===== fused MLP head (bf16 MFMA) + softmax =====
    mlp_mfma<<<(N + NB - 1) / NB, 512, 0, stream>>>(m0b, w1p, lb1, w2p, lb2, w3p, lb3, out, N);
}